// Round 7
// baseline (365.380 us; speedup 1.0000x reference)
//
#include <hip/hip_runtime.h>
#include <hip/hip_bf16.h>
#include <stdint.h>

// Problem constants (match setup_inputs)
#define B_  4
#define S_  2048
#define E_  1024
#define H_  16
#define HD_ 64
#define JD_ 25            // observation_dim + action_dim + 2
#define M_  (B_ * S_)     // 8192 rows for the projections
#define SE_ ((size_t)B_ * S_ * E_)          // 8,388,608
#define EE_ ((size_t)E_ * E_)               // 1,048,576

// Q pre-scale: (1/sqrt(64)) * log2(e) -> scores in log2 domain, exp2 softmax
#define QSCALE 0.18033688011112042f

// workspace layout (ushort units)
#define OFF_HSB  ((size_t)0)
#define OFF_W(i) (SE_ + (size_t)(i) * EE_)
#define OFF_B(i) (SE_ + 4 * EE_ + (size_t)(i) * E_)
#define OFF_Q    (SE_ + 4 * EE_ + 4 * (size_t)E_)
#define OFF_K    (OFF_Q + SE_)
#define OFF_V    (OFF_K + SE_)   // holds V^T: [feature][b*S+s], row stride M_
#define OFF_O    (OFF_V + SE_)

typedef __attribute__((ext_vector_type(8))) short bf16x8;  // 8 bf16 = 4 VGPRs
typedef __attribute__((ext_vector_type(4))) float f32x4;

__device__ __forceinline__ float b2f(ushort u) {
  union { uint32_t i; float f; } x; x.i = ((uint32_t)u) << 16; return x.f;
}
__device__ __forceinline__ ushort f2b(float f) {
  union { float f; uint32_t i; } x; x.f = f;
  uint32_t i = x.i;
  uint32_t r = (i + 0x7FFFu + ((i >> 16) & 1u)) >> 16;
  return (ushort)r;
}

// packed f32x2 -> bf16x2 (RNE); HW v_cvt_pk_bf16_f32 when available
#if __has_builtin(__builtin_amdgcn_cvt_pk_bf16_f32)
__device__ __forceinline__ uint32_t pkbf(float a, float b) {
  auto v = __builtin_amdgcn_cvt_pk_bf16_f32(a, b);
  uint32_t u; __builtin_memcpy(&u, &v, 4); return u;
}
#else
__device__ __forceinline__ uint32_t pkbf(float a, float b) {
  return (uint32_t)f2b(a) | ((uint32_t)f2b(b) << 16);
}
#endif

// workgroup barrier WITHOUT vmcnt drain (keeps global_load_lds prefetch in
// flight). lgkmcnt(0) for LDS-order safety; "memory" stops reordering.
__device__ __forceinline__ void wg_barrier_novm() {
  asm volatile("s_waitcnt lgkmcnt(0)\n\ts_barrier" ::: "memory");
}

// Runtime dtype detection on hidden_states (bf16-served vs fp32-served).
__device__ bool detect_bf16(const ushort* det) {
  int sane = 0;
#pragma unroll
  for (int i = 0; i < 32; ++i) {
    ushort u = det[2 * i];
    int e = (u >> 7) & 0xFF;
    sane += (e >= 90 && e <= 150) ? 1 : 0;
  }
  return sane >= 24;
}

__device__ __forceinline__ void async16(const void* g, void* l) {
  __builtin_amdgcn_global_load_lds(
      (const __attribute__((address_space(1))) uint32_t*)g,
      (__attribute__((address_space(3))) uint32_t*)l, 16, 0, 0);
}

// ============================================================================
// Normalize all float inputs to bf16 copies in ws.
// ============================================================================
__global__ __launch_bounds__(256)
void convert_kernel(const void* hs, const void* wq, const void* wk,
                    const void* wv, const void* wp,
                    const void* bq, const void* bk, const void* bv, const void* bp,
                    ushort* ws)
{
  __shared__ int dflag;
  if (threadIdx.x == 0) dflag = detect_bf16((const ushort*)hs) ? 1 : 0;
  __syncthreads();
  const bool isb = (dflag != 0);

  const void* src; ushort* dst; size_t n;
  switch (blockIdx.y) {
    case 0: src = hs; dst = ws + OFF_HSB;  n = SE_;        break;
    case 1: src = wq; dst = ws + OFF_W(0); n = EE_;        break;
    case 2: src = wk; dst = ws + OFF_W(1); n = EE_;        break;
    case 3: src = wv; dst = ws + OFF_W(2); n = EE_;        break;
    case 4: src = wp; dst = ws + OFF_W(3); n = EE_;        break;
    case 5: src = bq; dst = ws + OFF_B(0); n = (size_t)E_; break;
    case 6: src = bk; dst = ws + OFF_B(1); n = (size_t)E_; break;
    case 7: src = bv; dst = ws + OFF_B(2); n = (size_t)E_; break;
    default: src = bp; dst = ws + OFF_B(3); n = (size_t)E_; break;
  }
  size_t nv = n >> 2;
  for (size_t i = blockIdx.x * (size_t)blockDim.x + threadIdx.x; i < nv;
       i += (size_t)gridDim.x * blockDim.x) {
    ushort4 o;
    if (isb) {
      o = ((const ushort4*)src)[i];
    } else {
      float4 f = ((const float4*)src)[i];
      o.x = f2b(f.x); o.y = f2b(f.y); o.z = f2b(f.z); o.w = f2b(f.w);
    }
    ((ushort4*)dst)[i] = o;
  }
}

// ============================================================================
// NT GEMM: C[M,N] = (A[M,K] * W[N,K]^T + bias) * scale  (bf16 in, fp32 acc)
// 128x128 tile, BK=32, 256 threads. grid.z selects (W,bias,C).
// tz: z stored TRANSPOSED [N][M] (V^T). scalez: z scaled by QSCALE.
// detect_out=1: C dtype (f32 vs bf16) chosen at runtime per detect_bf16(det).
// ============================================================================
__global__ __launch_bounds__(256, 2)
void gemm_nt_bias(const ushort* __restrict__ X,
                  const ushort* __restrict__ W0, const ushort* __restrict__ b0, void* __restrict__ C0,
                  const ushort* __restrict__ W1, const ushort* __restrict__ b1, void* __restrict__ C1,
                  const ushort* __restrict__ W2, const ushort* __restrict__ b2, void* __restrict__ C2,
                  int M, int N, int Kd, const ushort* det, int detect_out, int tz, int scalez)
{
  const ushort* W  = (blockIdx.z == 0) ? W0 : (blockIdx.z == 1) ? W1 : W2;
  const ushort* bi = (blockIdx.z == 0) ? b0 : (blockIdx.z == 1) ? b1 : b2;
  void*         C  = (blockIdx.z == 0) ? C0 : (blockIdx.z == 1) ? C1 : C2;
  const bool tstore = ((int)blockIdx.z == tz);
  const float scl  = ((int)blockIdx.z == scalez) ? QSCALE : 1.0f;

  __shared__ ushort lA[128 * 32];
  __shared__ ushort lB[128 * 32];
  __shared__ int dflag;
  if (threadIdx.x == 0) dflag = (detect_out && !detect_bf16(det)) ? 1 : 0;
  __syncthreads();
  const bool f32out = (dflag != 0);

  const int tid  = threadIdx.x;
  const int lane = tid & 63;
  const int wv   = tid >> 6;
  const int m0   = blockIdx.x * 128;
  const int n0   = blockIdx.y * 128;
  const int wr   = (wv >> 1) * 64;
  const int wc   = (wv & 1) * 64;
  const int ml   = lane & 15;
  const int qd   = lane >> 4;

  f32x4 acc[4][4];
#pragma unroll
  for (int i = 0; i < 4; ++i)
#pragma unroll
    for (int j = 0; j < 4; ++j)
      acc[i][j] = (f32x4){0.f, 0.f, 0.f, 0.f};

  const int rowA = tid >> 2;
  const int kvec = (tid & 3) * 8;
  const ushort* gA = X + (size_t)(m0 + rowA) * Kd + kvec;
  const ushort* gW = W + (size_t)(n0 + rowA) * Kd + kvec;
  char* lAb = (char*)lA + (size_t)wv * 1024;
  char* lBb = (char*)lB + (size_t)wv * 1024;

  for (int k0 = 0; k0 < Kd; k0 += 32) {
    async16(gA + k0,                    lAb);
    async16(gA + k0 + (size_t)64 * Kd,  lAb + 4096);
    async16(gW + k0,                    lBb);
    async16(gW + k0 + (size_t)64 * Kd,  lBb + 4096);
    __syncthreads();

    bf16x8 af[4], bfr[4];
#pragma unroll
    for (int i = 0; i < 4; ++i)
      af[i] = *(const bf16x8*)&lA[(wr + i * 16 + ml) * 32 + qd * 8];
#pragma unroll
    for (int j = 0; j < 4; ++j)
      bfr[j] = *(const bf16x8*)&lB[(wc + j * 16 + ml) * 32 + qd * 8];
#pragma unroll
    for (int i = 0; i < 4; ++i)
#pragma unroll
      for (int j = 0; j < 4; ++j)
        acc[i][j] = __builtin_amdgcn_mfma_f32_16x16x32_bf16(af[i], bfr[j], acc[i][j], 0, 0, 0);
    __syncthreads();
  }

  // epilogue: C/D layout col=lane&15, row=quad*4+reg
#pragma unroll
  for (int j = 0; j < 4; ++j) {
    int col = n0 + wc + j * 16 + ml;
    float bv = b2f(bi[col]);
#pragma unroll
    for (int i = 0; i < 4; ++i) {
      int row0 = m0 + wr + i * 16 + qd * 4;
      if (tstore) {
        uint2 pk;
        pk.x = pkbf((acc[i][j][0] + bv) * scl, (acc[i][j][1] + bv) * scl);
        pk.y = pkbf((acc[i][j][2] + bv) * scl, (acc[i][j][3] + bv) * scl);
        *(uint2*)((ushort*)C + (size_t)col * M + row0) = pk;
      } else if (f32out) {
        float* cp = (float*)C + (size_t)row0 * N + col;
#pragma unroll
        for (int r = 0; r < 4; ++r)
          cp[(size_t)r * N] = (acc[i][j][r] + bv) * scl;
      } else {
        ushort* cp = (ushort*)C + (size_t)row0 * N + col;
#pragma unroll
        for (int r = 0; r < 4; ++r)
          cp[(size_t)r * N] = f2b((acc[i][j][r] + bv) * scl);
      }
    }
  }
}

// ============================================================================
// Flash attention, periodic causal mask. Q pre-scaled by 0.125*log2e.
// Transposed scores: S^T = K(A)*Q(B), per-lane softmax rows, O^T=V^T(A)*P^T(B).
// K/V staged by global_load_lds(16B) into XOR-swizzled LDS, double-buffered.
// P^T overlays the CURRENT K buffer (dead after S-phase): iteration =
//   __syncthreads (drains prefetch kt) -> issue kt+1 -> S-phase (both tiles)
//   -> raw s_barrier (NO vmcnt drain) -> P/PV-phase (P into K[cur] slice).
// LDS = 32KB -> up to 5 blocks/CU. Bad-column mask = per-lane additive bias
// built once per kt; full causal bitmask only on each tile's diagonal kt.
// ============================================================================
__global__ __launch_bounds__(256, 4)
void attn_kernel(const ushort* __restrict__ Qg, const ushort* __restrict__ Kg,
                 const ushort* __restrict__ Vt, ushort* __restrict__ Og)
{
  __shared__ ushort lK[2][64 * 64];   // [key][d] swizzled; P^T overlays cur
  __shared__ ushort lV[2][64 * 64];   // [d][key] swizzled

  // XCD-aware decode: xcd = lin&7; all 16 p-blocks of a bh on one XCD
  const int lin = blockIdx.x;
  const int bh  = (lin & 7) * 8 + (lin >> 7);       // 0..63
  const int p   = (lin >> 3) & 15;                  // 0..15
  const int b = bh >> 4, h = bh & 15;
  const size_t base = (size_t)b * S_ * E_ + (size_t)h * HD_;   // Q,K,O
  const ushort* vtb = Vt + (size_t)(h * HD_) * M_ + (size_t)b * S_;

  const int tid  = threadIdx.x;
  const int lane = tid & 63;
  const int wv   = tid >> 6;
  const int ml   = lane & 15;
  const int qd   = lane >> 4;
  const int sx   = ml & 7;            // XOR swizzle key for this lane's reads

  const int qthi = 31 - p, qtlo = p;
  const int q0t[2] = { qthi * 64 + wv * 16, qtlo * 64 + wv * 16 };
  const int ktmax = qthi;

  // Q B-frags: lane n=ml -> query q0t[T]+ml; k = half*32 + qd*8 + j
  bf16x8 qf[2][2];
#pragma unroll
  for (int T = 0; T < 2; ++T) {
    const ushort* qp = Qg + base + (size_t)(q0t[T] + ml) * E_ + qd * 8;
    qf[T][0] = *(const bf16x8*)qp;
    qf[T][1] = *(const bf16x8*)(qp + 32);
  }

  f32x4 oacc[2][4];
  float m_i[2], l_i[2];
#pragma unroll
  for (int T = 0; T < 2; ++T) {
#pragma unroll
    for (int nb = 0; nb < 4; ++nb) oacc[T][nb] = (f32x4){0.f, 0.f, 0.f, 0.f};
    m_i[T] = -1.0e30f; l_i[T] = 0.f;
  }

  // staging: 8 rounds of 1KB (4 waves x 2); lane covers 16B chunk g.
  const int g0 = (wv * 2) * 64 + lane;
  const int g1 = g0 + 64;
  const int r0 = g0 >> 3, c0 = ((g0 & 7) ^ (r0 & 7)) * 8;
  const int r1 = g1 >> 3, c1 = ((g1 & 7) ^ (r1 & 7)) * 8;
  const ushort* kS0 = Kg + base + (size_t)r0 * E_ + c0;
  const ushort* kS1 = Kg + base + (size_t)r1 * E_ + c1;
  const ushort* vS0 = vtb + (size_t)r0 * M_ + c0;
  const ushort* vS1 = vtb + (size_t)r1 * M_ + c1;
  const int d0 = (wv * 2) * 512, d1 = d0 + 512;

#define ISSUE(bi_, t_) { size_t ko = (size_t)(t_) * 64 * E_; int vo = (t_) * 64; \
    async16(kS0 + ko, &lK[bi_][d0]); async16(kS1 + ko, &lK[bi_][d1]);            \
    async16(vS0 + vo, &lV[bi_][d0]); async16(vS1 + vo, &lV[bi_][d1]); }

  ISSUE(0, 0);

  for (int kt = 0; kt <= ktmax; ++kt) {
    __syncthreads();                   // drains tile-kt loads; prev P/PV done
    if (kt < ktmax) ISSUE((kt + 1) & 1, kt + 1);
    const ushort* bK = lK[kt & 1];
    const ushort* bV = lV[kt & 1];

    // wave-uniform bad-column bitmask; per-lane additive bias (both tiles)
    uint64_t bad = 0;
    {
      int rem = (kt * 64) % JD_;
      int pp = JD_ - 1 - rem;
      for (; pp < 64; pp += JD_) bad |= 1ull << pp;
    }
    float bb[4][4];
#pragma unroll
    for (int kb = 0; kb < 4; ++kb) {
      uint32_t b4 = (uint32_t)(bad >> (kb * 16 + qd * 4)) & 0xFu;
#pragma unroll
      for (int r = 0; r < 4; ++r)
        bb[kb][r] = ((b4 >> r) & 1u) ? -1.0e30f : 0.0f;
    }

    uint2 pb[2][4];                    // packed P^T rows per tile
    const bool act[2] = { true, kt <= qtlo };

    // ================= S-phase (reads bK) =================
#pragma unroll
    for (int T = 0; T < 2; ++T) {
      if (!act[T]) continue;
      const int q0w = q0t[T];
      float sc[4][4];
#pragma unroll
      for (int kb = 0; kb < 4; ++kb) {
        f32x4 s = (f32x4){0.f, 0.f, 0.f, 0.f};
        const ushort* krow = &bK[(kb * 16 + ml) * 64];
        s = __builtin_amdgcn_mfma_f32_16x16x32_bf16(*(const bf16x8*)&krow[(qd ^ sx) * 8],       qf[T][0], s, 0, 0, 0);
        s = __builtin_amdgcn_mfma_f32_16x16x32_bf16(*(const bf16x8*)&krow[((qd + 4) ^ sx) * 8], qf[T][1], s, 0, 0, 0);
#pragma unroll
        for (int r = 0; r < 4; ++r) sc[kb][r] = s[r];
      }
      if (kt == (q0w >> 6)) {          // diagonal tile: full causal+bad mask
        const int qrel = q0w + ml - kt * 64;
        uint64_t keep = (qrel >= 63) ? ~0ull : ((1ull << (qrel + 1)) - 1ull);
        keep &= ~bad;
        const uint64_t ks = keep >> (qd * 4);
        const uint32_t k_lo = (uint32_t)ks, k_hi = (uint32_t)(ks >> 32);
#pragma unroll
        for (int kb = 0; kb < 4; ++kb) {
          const uint32_t kh = (kb & 1) ? ((kb & 2) ? (k_hi >> 16) : (k_lo >> 16))
                                       : ((kb & 2) ? k_hi : k_lo);
#pragma unroll
          for (int r = 0; r < 4; ++r)
            sc[kb][r] = ((kh >> r) & 1u) ? sc[kb][r] : -1.0e30f;
        }
      } else {                         // interior tile: bad-col bias only
#pragma unroll
        for (int kb = 0; kb < 4; ++kb)
#pragma unroll
          for (int r = 0; r < 4; ++r) sc[kb][r] += bb[kb][r];
      }

      // softmax (per-lane row, 2 shuffles cross-quad)
      float mx = sc[0][0];
#pragma unroll
      for (int kb = 0; kb < 4; ++kb)
#pragma unroll
        for (int r = 0; r < 4; ++r) mx = fmaxf(mx, sc[kb][r]);
      mx = fmaxf(mx, __shfl_xor(mx, 16));
      mx = fmaxf(mx, __shfl_xor(mx, 32));
      const float mn = fmaxf(m_i[T], mx);
      const float al = __builtin_exp2f(m_i[T] - mn);
      m_i[T] = mn;
      float rs = 0.f;
#pragma unroll
      for (int kb = 0; kb < 4; ++kb)
#pragma unroll
        for (int r = 0; r < 4; ++r) {
          float pv = __builtin_exp2f(sc[kb][r] - mn);
          sc[kb][r] = pv; rs += pv;
        }
      rs += __shfl_xor(rs, 16);
      rs += __shfl_xor(rs, 32);
      l_i[T] = l_i[T] * al + rs;
#pragma unroll
      for (int nb = 0; nb < 4; ++nb)
#pragma unroll
        for (int r = 0; r < 4; ++r) oacc[T][nb][r] *= al;
#pragma unroll
      for (int kb = 0; kb < 4; ++kb) {
        pb[T][kb].x = pkbf(sc[kb][0], sc[kb][1]);
        pb[T][kb].y = pkbf(sc[kb][2], sc[kb][3]);
      }
    }

    // all waves done reading bK; prefetch stays in flight (no vmcnt drain)
    wg_barrier_novm();

    // ================= P/PV-phase (P^T overlays bK slice) =================
    ushort* pw = (ushort*)&lK[kt & 1][wv * 1024];
#pragma unroll
    for (int T = 0; T < 2; ++T) {
      if (!act[T]) continue;
      const int sub = (qd & 1) * 4;
#pragma unroll
      for (int kb = 0; kb < 4; ++kb) {
        const int s_ = (kb * 2 + (qd >> 1)) ^ sx;
        *(uint2*)&pw[ml * 64 + s_ * 8 + sub] = pb[T][kb];
      }
      // same-wave in-order DS: no barrier needed
      bf16x8 pa0 = *(const bf16x8*)&pw[ml * 64 + (qd ^ sx) * 8];
      bf16x8 pa1 = *(const bf16x8*)&pw[ml * 64 + ((qd + 4) ^ sx) * 8];
#pragma unroll
      for (int nb = 0; nb < 4; ++nb) {
        const ushort* vrow = &bV[(nb * 16 + ml) * 64];
        oacc[T][nb] = __builtin_amdgcn_mfma_f32_16x16x32_bf16(*(const bf16x8*)&vrow[(qd ^ sx) * 8],       pa0, oacc[T][nb], 0, 0, 0);
        oacc[T][nb] = __builtin_amdgcn_mfma_f32_16x16x32_bf16(*(const bf16x8*)&vrow[((qd + 4) ^ sx) * 8], pa1, oacc[T][nb], 0, 0, 0);
      }
    }
  }
#undef ISSUE

  // epilogue: lane owns query q0t[T]+ml; d = nb*16 + qd*4 + r (4 contiguous)
#pragma unroll
  for (int T = 0; T < 2; ++T) {
    const float inv = 1.0f / l_i[T];
    const int q = q0t[T] + ml;
#pragma unroll
    for (int nb = 0; nb < 4; ++nb) {
      uint2 o;
      o.x = pkbf(oacc[T][nb][0] * inv, oacc[T][nb][1] * inv);
      o.y = pkbf(oacc[T][nb][2] * inv, oacc[T][nb][3] * inv);
      *(uint2*)&Og[base + (size_t)q * E_ + nb * 16 + qd * 4] = o;
    }
  }
}

// ============================================================================
extern "C" void kernel_launch(void* const* d_in, const int* in_sizes, int n_in,
                              void* d_out, int out_size, void* d_ws, size_t ws_size,
                              hipStream_t stream) {
  const void* hs = d_in[0];
  const void* Wq = d_in[1];
  const void* bq = d_in[2];
  const void* Wk = d_in[3];
  const void* bk = d_in[4];
  const void* Wv = d_in[5];
  const void* bv = d_in[6];
  const void* Wp = d_in[7];
  const void* bp = d_in[8];

  ushort* ws = (ushort*)d_ws;
  ushort* hsb = ws + OFF_HSB;
  ushort* Wqb = ws + OFF_W(0);
  ushort* Wkb = ws + OFF_W(1);
  ushort* Wvb = ws + OFF_W(2);
  ushort* Wpb = ws + OFF_W(3);
  ushort* bqb = ws + OFF_B(0);
  ushort* bkb = ws + OFF_B(1);
  ushort* bvb = ws + OFF_B(2);
  ushort* bpb = ws + OFF_B(3);
  ushort* Qw  = ws + OFF_Q;
  ushort* Kw  = ws + OFF_K;
  ushort* Vw  = ws + OFF_V;   // V^T [feature][b*S+s]
  ushort* Ow  = ws + OFF_O;
  const ushort* det = (const ushort*)hs;

  dim3 blk(256, 1, 1);
  hipLaunchKernelGGL(convert_kernel, dim3(512, 9, 1), blk, 0, stream,
                     hs, Wq, Wk, Wv, Wp, bq, bk, bv, bp, ws);
  // fused QKV projections; z==2 (V) transposed store; z==0 (Q) scaled QSCALE
  hipLaunchKernelGGL(gemm_nt_bias, dim3(M_ / 128, E_ / 128, 3), blk, 0, stream,
                     hsb, Wqb, bqb, (void*)Qw, Wkb, bkb, (void*)Kw,
                     Wvb, bvb, (void*)Vw, M_, E_, E_, det, 0, 2, 0);
  // attention: 1024 1D blocks, XCD-swizzled
  hipLaunchKernelGGL(attn_kernel, dim3(1024, 1, 1), blk, 0, stream,
                     Qw, Kw, Vw, Ow);
  // output projection: d_out dtype detected at runtime
  hipLaunchKernelGGL(gemm_nt_bias, dim3(M_ / 128, E_ / 128, 1), blk, 0, stream,
                     Ow, Wpb, bpb, d_out, Wpb, bpb, d_out, Wpb, bpb, d_out,
                     M_, E_, E_, det, 1, -1, -1);
}

// Round 8
// 332.656 us; speedup vs baseline: 1.0984x; 1.0984x over previous
//
#include <hip/hip_runtime.h>
#include <hip/hip_bf16.h>
#include <stdint.h>

// Problem constants (match setup_inputs)
#define B_  4
#define S_  2048
#define E_  1024
#define H_  16
#define HD_ 64
#define JD_ 25            // observation_dim + action_dim + 2
#define M_  (B_ * S_)     // 8192 rows for the projections
#define SE_ ((size_t)B_ * S_ * E_)          // 8,388,608
#define EE_ ((size_t)E_ * E_)               // 1,048,576

// Q pre-scale: (1/sqrt(64)) * log2(e) -> scores in log2 domain, exp2 softmax
#define QSCALE 0.18033688011112042f

// workspace layout (ushort units)
#define OFF_HSB  ((size_t)0)
#define OFF_W(i) (SE_ + (size_t)(i) * EE_)
#define OFF_B(i) (SE_ + 4 * EE_ + (size_t)(i) * E_)
#define OFF_Q    (SE_ + 4 * EE_ + 4 * (size_t)E_)
#define OFF_K    (OFF_Q + SE_)
#define OFF_V    (OFF_K + SE_)   // holds V^T: [feature][b*S+s], row stride M_
#define OFF_O    (OFF_V + SE_)

typedef __attribute__((ext_vector_type(8))) short bf16x8;  // 8 bf16 = 4 VGPRs
typedef __attribute__((ext_vector_type(4))) float f32x4;

__device__ __forceinline__ float b2f(ushort u) {
  union { uint32_t i; float f; } x; x.i = ((uint32_t)u) << 16; return x.f;
}
__device__ __forceinline__ ushort f2b(float f) {
  union { float f; uint32_t i; } x; x.f = f;
  uint32_t i = x.i;
  uint32_t r = (i + 0x7FFFu + ((i >> 16) & 1u)) >> 16;
  return (ushort)r;
}

// packed f32x2 -> bf16x2 (RNE); HW v_cvt_pk_bf16_f32 when available
#if __has_builtin(__builtin_amdgcn_cvt_pk_bf16_f32)
__device__ __forceinline__ uint32_t pkbf(float a, float b) {
  auto v = __builtin_amdgcn_cvt_pk_bf16_f32(a, b);
  uint32_t u; __builtin_memcpy(&u, &v, 4); return u;
}
#else
__device__ __forceinline__ uint32_t pkbf(float a, float b) {
  return (uint32_t)f2b(a) | ((uint32_t)f2b(b) << 16);
}
#endif

// workgroup barrier WITHOUT vmcnt drain (keeps global_load_lds prefetch in
// flight). lgkmcnt(0) for LDS-order safety; "memory" stops reordering.
__device__ __forceinline__ void wg_barrier_novm() {
  asm volatile("s_waitcnt lgkmcnt(0)\n\ts_barrier" ::: "memory");
}

// Runtime dtype detection on hidden_states (bf16-served vs fp32-served).
__device__ bool detect_bf16(const ushort* det) {
  int sane = 0;
#pragma unroll
  for (int i = 0; i < 32; ++i) {
    ushort u = det[2 * i];
    int e = (u >> 7) & 0xFF;
    sane += (e >= 90 && e <= 150) ? 1 : 0;
  }
  return sane >= 24;
}

__device__ __forceinline__ void async16(const void* g, void* l) {
  __builtin_amdgcn_global_load_lds(
      (const __attribute__((address_space(1))) uint32_t*)g,
      (__attribute__((address_space(3))) uint32_t*)l, 16, 0, 0);
}

// ============================================================================
// Normalize all float inputs to bf16 copies in ws.
// ============================================================================
__global__ __launch_bounds__(256)
void convert_kernel(const void* hs, const void* wq, const void* wk,
                    const void* wv, const void* wp,
                    const void* bq, const void* bk, const void* bv, const void* bp,
                    ushort* ws)
{
  __shared__ int dflag;
  if (threadIdx.x == 0) dflag = detect_bf16((const ushort*)hs) ? 1 : 0;
  __syncthreads();
  const bool isb = (dflag != 0);

  const void* src; ushort* dst; size_t n;
  switch (blockIdx.y) {
    case 0: src = hs; dst = ws + OFF_HSB;  n = SE_;        break;
    case 1: src = wq; dst = ws + OFF_W(0); n = EE_;        break;
    case 2: src = wk; dst = ws + OFF_W(1); n = EE_;        break;
    case 3: src = wv; dst = ws + OFF_W(2); n = EE_;        break;
    case 4: src = wp; dst = ws + OFF_W(3); n = EE_;        break;
    case 5: src = bq; dst = ws + OFF_B(0); n = (size_t)E_; break;
    case 6: src = bk; dst = ws + OFF_B(1); n = (size_t)E_; break;
    case 7: src = bv; dst = ws + OFF_B(2); n = (size_t)E_; break;
    default: src = bp; dst = ws + OFF_B(3); n = (size_t)E_; break;
  }
  size_t nv = n >> 2;
  for (size_t i = blockIdx.x * (size_t)blockDim.x + threadIdx.x; i < nv;
       i += (size_t)gridDim.x * blockDim.x) {
    ushort4 o;
    if (isb) {
      o = ((const ushort4*)src)[i];
    } else {
      float4 f = ((const float4*)src)[i];
      o.x = f2b(f.x); o.y = f2b(f.y); o.z = f2b(f.z); o.w = f2b(f.w);
    }
    ((ushort4*)dst)[i] = o;
  }
}

// ============================================================================
// NT GEMM: C[M,N] = (A[M,K] * W[N,K]^T + bias) * scale  (bf16 in, fp32 acc)
// 128x128 tile, BK=32, 256 threads. grid.z selects (W,bias,C).
// tz: z stored TRANSPOSED [N][M] (V^T). scalez: z scaled by QSCALE.
// detect_out=1: C dtype (f32 vs bf16) chosen at runtime per detect_bf16(det).
// ============================================================================
__global__ __launch_bounds__(256, 2)
void gemm_nt_bias(const ushort* __restrict__ X,
                  const ushort* __restrict__ W0, const ushort* __restrict__ b0, void* __restrict__ C0,
                  const ushort* __restrict__ W1, const ushort* __restrict__ b1, void* __restrict__ C1,
                  const ushort* __restrict__ W2, const ushort* __restrict__ b2, void* __restrict__ C2,
                  int M, int N, int Kd, const ushort* det, int detect_out, int tz, int scalez)
{
  const ushort* W  = (blockIdx.z == 0) ? W0 : (blockIdx.z == 1) ? W1 : W2;
  const ushort* bi = (blockIdx.z == 0) ? b0 : (blockIdx.z == 1) ? b1 : b2;
  void*         C  = (blockIdx.z == 0) ? C0 : (blockIdx.z == 1) ? C1 : C2;
  const bool tstore = ((int)blockIdx.z == tz);
  const float scl  = ((int)blockIdx.z == scalez) ? QSCALE : 1.0f;

  __shared__ ushort lA[128 * 32];
  __shared__ ushort lB[128 * 32];
  __shared__ int dflag;
  if (threadIdx.x == 0) dflag = (detect_out && !detect_bf16(det)) ? 1 : 0;
  __syncthreads();
  const bool f32out = (dflag != 0);

  const int tid  = threadIdx.x;
  const int lane = tid & 63;
  const int wv   = tid >> 6;
  const int m0   = blockIdx.x * 128;
  const int n0   = blockIdx.y * 128;
  const int wr   = (wv >> 1) * 64;
  const int wc   = (wv & 1) * 64;
  const int ml   = lane & 15;
  const int qd   = lane >> 4;

  f32x4 acc[4][4];
#pragma unroll
  for (int i = 0; i < 4; ++i)
#pragma unroll
    for (int j = 0; j < 4; ++j)
      acc[i][j] = (f32x4){0.f, 0.f, 0.f, 0.f};

  const int rowA = tid >> 2;
  const int kvec = (tid & 3) * 8;
  const ushort* gA = X + (size_t)(m0 + rowA) * Kd + kvec;
  const ushort* gW = W + (size_t)(n0 + rowA) * Kd + kvec;
  char* lAb = (char*)lA + (size_t)wv * 1024;
  char* lBb = (char*)lB + (size_t)wv * 1024;

  for (int k0 = 0; k0 < Kd; k0 += 32) {
    async16(gA + k0,                    lAb);
    async16(gA + k0 + (size_t)64 * Kd,  lAb + 4096);
    async16(gW + k0,                    lBb);
    async16(gW + k0 + (size_t)64 * Kd,  lBb + 4096);
    __syncthreads();

    bf16x8 af[4], bfr[4];
#pragma unroll
    for (int i = 0; i < 4; ++i)
      af[i] = *(const bf16x8*)&lA[(wr + i * 16 + ml) * 32 + qd * 8];
#pragma unroll
    for (int j = 0; j < 4; ++j)
      bfr[j] = *(const bf16x8*)&lB[(wc + j * 16 + ml) * 32 + qd * 8];
#pragma unroll
    for (int i = 0; i < 4; ++i)
#pragma unroll
      for (int j = 0; j < 4; ++j)
        acc[i][j] = __builtin_amdgcn_mfma_f32_16x16x32_bf16(af[i], bfr[j], acc[i][j], 0, 0, 0);
    __syncthreads();
  }

  // epilogue: C/D layout col=lane&15, row=quad*4+reg
#pragma unroll
  for (int j = 0; j < 4; ++j) {
    int col = n0 + wc + j * 16 + ml;
    float bv = b2f(bi[col]);
#pragma unroll
    for (int i = 0; i < 4; ++i) {
      int row0 = m0 + wr + i * 16 + qd * 4;
      if (tstore) {
        uint2 pk;
        pk.x = pkbf((acc[i][j][0] + bv) * scl, (acc[i][j][1] + bv) * scl);
        pk.y = pkbf((acc[i][j][2] + bv) * scl, (acc[i][j][3] + bv) * scl);
        *(uint2*)((ushort*)C + (size_t)col * M + row0) = pk;
      } else if (f32out) {
        float* cp = (float*)C + (size_t)row0 * N + col;
#pragma unroll
        for (int r = 0; r < 4; ++r)
          cp[(size_t)r * N] = (acc[i][j][r] + bv) * scl;
      } else {
        ushort* cp = (ushort*)C + (size_t)row0 * N + col;
#pragma unroll
        for (int r = 0; r < 4; ++r)
          cp[(size_t)r * N] = f2b((acc[i][j][r] + bv) * scl);
      }
    }
  }
}

// ============================================================================
// Flash attention, periodic causal mask. Q pre-scaled by 0.125*log2e.
// Transposed scores: S^T = K(A)*Q(B), per-lane softmax rows, O^T=V^T(A)*P^T(B).
// K/V staged by global_load_lds(16B) into XOR-swizzled LDS, double-buffered.
// P^T overlays the CURRENT K buffer (dead after S-phase): iteration =
//   __syncthreads (drains prefetch kt) -> issue kt+1 -> S-phase (both tiles)
//   -> raw s_barrier (NO vmcnt drain) -> P/PV-phase (P into K[cur] slice).
// LDS = 32KB. NOTE: __launch_bounds__ min-waves must stay 2 — the 2nd arg
// caps VGPRs at 256/min_waves on this toolchain; 4 caused spill (R5, R7).
// ============================================================================
__global__ __launch_bounds__(256, 2)
void attn_kernel(const ushort* __restrict__ Qg, const ushort* __restrict__ Kg,
                 const ushort* __restrict__ Vt, ushort* __restrict__ Og)
{
  __shared__ ushort lK[2][64 * 64];   // [key][d] swizzled; P^T overlays cur
  __shared__ ushort lV[2][64 * 64];   // [d][key] swizzled

  // XCD-aware decode: xcd = lin&7; all 16 p-blocks of a bh on one XCD
  const int lin = blockIdx.x;
  const int bh  = (lin & 7) * 8 + (lin >> 7);       // 0..63
  const int p   = (lin >> 3) & 15;                  // 0..15
  const int b = bh >> 4, h = bh & 15;
  const size_t base = (size_t)b * S_ * E_ + (size_t)h * HD_;   // Q,K,O
  const ushort* vtb = Vt + (size_t)(h * HD_) * M_ + (size_t)b * S_;

  const int tid  = threadIdx.x;
  const int lane = tid & 63;
  const int wv   = tid >> 6;
  const int ml   = lane & 15;
  const int qd   = lane >> 4;
  const int sx   = ml & 7;            // XOR swizzle key for this lane's reads

  const int qthi = 31 - p, qtlo = p;
  const int q0t[2] = { qthi * 64 + wv * 16, qtlo * 64 + wv * 16 };
  const int ktmax = qthi;

  // Q B-frags: lane n=ml -> query q0t[T]+ml; k = half*32 + qd*8 + j
  bf16x8 qf[2][2];
#pragma unroll
  for (int T = 0; T < 2; ++T) {
    const ushort* qp = Qg + base + (size_t)(q0t[T] + ml) * E_ + qd * 8;
    qf[T][0] = *(const bf16x8*)qp;
    qf[T][1] = *(const bf16x8*)(qp + 32);
  }

  f32x4 oacc[2][4];
  float m_i[2], l_i[2];
#pragma unroll
  for (int T = 0; T < 2; ++T) {
#pragma unroll
    for (int nb = 0; nb < 4; ++nb) oacc[T][nb] = (f32x4){0.f, 0.f, 0.f, 0.f};
    m_i[T] = -1.0e30f; l_i[T] = 0.f;
  }

  // staging: 8 rounds of 1KB (4 waves x 2); lane covers 16B chunk g.
  const int g0 = (wv * 2) * 64 + lane;
  const int g1 = g0 + 64;
  const int r0 = g0 >> 3, c0 = ((g0 & 7) ^ (r0 & 7)) * 8;
  const int r1 = g1 >> 3, c1 = ((g1 & 7) ^ (r1 & 7)) * 8;
  const ushort* kS0 = Kg + base + (size_t)r0 * E_ + c0;
  const ushort* kS1 = Kg + base + (size_t)r1 * E_ + c1;
  const ushort* vS0 = vtb + (size_t)r0 * M_ + c0;
  const ushort* vS1 = vtb + (size_t)r1 * M_ + c1;
  const int d0 = (wv * 2) * 512, d1 = d0 + 512;

#define ISSUE(bi_, t_) { size_t ko = (size_t)(t_) * 64 * E_; int vo = (t_) * 64; \
    async16(kS0 + ko, &lK[bi_][d0]); async16(kS1 + ko, &lK[bi_][d1]);            \
    async16(vS0 + vo, &lV[bi_][d0]); async16(vS1 + vo, &lV[bi_][d1]); }

  ISSUE(0, 0);

  for (int kt = 0; kt <= ktmax; ++kt) {
    __syncthreads();                   // drains tile-kt loads; prev P/PV done
    if (kt < ktmax) ISSUE((kt + 1) & 1, kt + 1);
    const ushort* bK = lK[kt & 1];
    const ushort* bV = lV[kt & 1];

    // wave-uniform bad-column bitmask; per-lane additive bias (both tiles)
    uint64_t bad = 0;
    {
      int rem = (kt * 64) % JD_;
      int pp = JD_ - 1 - rem;
      for (; pp < 64; pp += JD_) bad |= 1ull << pp;
    }
    float bb[4][4];
#pragma unroll
    for (int kb = 0; kb < 4; ++kb) {
      uint32_t b4 = (uint32_t)(bad >> (kb * 16 + qd * 4)) & 0xFu;
#pragma unroll
      for (int r = 0; r < 4; ++r)
        bb[kb][r] = ((b4 >> r) & 1u) ? -1.0e30f : 0.0f;
    }

    uint2 pb[2][4];                    // packed P^T rows per tile
    const bool act[2] = { true, kt <= qtlo };

    // ================= S-phase (reads bK) =================
#pragma unroll
    for (int T = 0; T < 2; ++T) {
      if (!act[T]) continue;
      const int q0w = q0t[T];
      float sc[4][4];
#pragma unroll
      for (int kb = 0; kb < 4; ++kb) {
        f32x4 s = (f32x4){0.f, 0.f, 0.f, 0.f};
        const ushort* krow = &bK[(kb * 16 + ml) * 64];
        s = __builtin_amdgcn_mfma_f32_16x16x32_bf16(*(const bf16x8*)&krow[(qd ^ sx) * 8],       qf[T][0], s, 0, 0, 0);
        s = __builtin_amdgcn_mfma_f32_16x16x32_bf16(*(const bf16x8*)&krow[((qd + 4) ^ sx) * 8], qf[T][1], s, 0, 0, 0);
#pragma unroll
        for (int r = 0; r < 4; ++r) sc[kb][r] = s[r];
      }
      if (kt == (q0w >> 6)) {          // diagonal tile: full causal+bad mask
        const int qrel = q0w + ml - kt * 64;
        uint64_t keep = (qrel >= 63) ? ~0ull : ((1ull << (qrel + 1)) - 1ull);
        keep &= ~bad;
        const uint64_t ks = keep >> (qd * 4);
        const uint32_t k_lo = (uint32_t)ks, k_hi = (uint32_t)(ks >> 32);
#pragma unroll
        for (int kb = 0; kb < 4; ++kb) {
          const uint32_t kh = (kb & 1) ? ((kb & 2) ? (k_hi >> 16) : (k_lo >> 16))
                                       : ((kb & 2) ? k_hi : k_lo);
#pragma unroll
          for (int r = 0; r < 4; ++r)
            sc[kb][r] = ((kh >> r) & 1u) ? sc[kb][r] : -1.0e30f;
        }
      } else {                         // interior tile: bad-col bias only
#pragma unroll
        for (int kb = 0; kb < 4; ++kb)
#pragma unroll
          for (int r = 0; r < 4; ++r) sc[kb][r] += bb[kb][r];
      }

      // softmax (per-lane row, 2 shuffles cross-quad)
      float mx = sc[0][0];
#pragma unroll
      for (int kb = 0; kb < 4; ++kb)
#pragma unroll
        for (int r = 0; r < 4; ++r) mx = fmaxf(mx, sc[kb][r]);
      mx = fmaxf(mx, __shfl_xor(mx, 16));
      mx = fmaxf(mx, __shfl_xor(mx, 32));
      const float mn = fmaxf(m_i[T], mx);
      const float al = __builtin_exp2f(m_i[T] - mn);
      m_i[T] = mn;
      float rs = 0.f;
#pragma unroll
      for (int kb = 0; kb < 4; ++kb)
#pragma unroll
        for (int r = 0; r < 4; ++r) {
          float pv = __builtin_exp2f(sc[kb][r] - mn);
          sc[kb][r] = pv; rs += pv;
        }
      rs += __shfl_xor(rs, 16);
      rs += __shfl_xor(rs, 32);
      l_i[T] = l_i[T] * al + rs;
#pragma unroll
      for (int nb = 0; nb < 4; ++nb)
#pragma unroll
        for (int r = 0; r < 4; ++r) oacc[T][nb][r] *= al;
#pragma unroll
      for (int kb = 0; kb < 4; ++kb) {
        pb[T][kb].x = pkbf(sc[kb][0], sc[kb][1]);
        pb[T][kb].y = pkbf(sc[kb][2], sc[kb][3]);
      }
    }

    // all waves done reading bK; prefetch stays in flight (no vmcnt drain)
    wg_barrier_novm();

    // ================= P/PV-phase (P^T overlays bK slice) =================
    ushort* pw = (ushort*)&lK[kt & 1][wv * 1024];
#pragma unroll
    for (int T = 0; T < 2; ++T) {
      if (!act[T]) continue;
      const int sub = (qd & 1) * 4;
#pragma unroll
      for (int kb = 0; kb < 4; ++kb) {
        const int s_ = (kb * 2 + (qd >> 1)) ^ sx;
        *(uint2*)&pw[ml * 64 + s_ * 8 + sub] = pb[T][kb];
      }
      // same-wave in-order DS: no barrier needed
      bf16x8 pa0 = *(const bf16x8*)&pw[ml * 64 + (qd ^ sx) * 8];
      bf16x8 pa1 = *(const bf16x8*)&pw[ml * 64 + ((qd + 4) ^ sx) * 8];
#pragma unroll
      for (int nb = 0; nb < 4; ++nb) {
        const ushort* vrow = &bV[(nb * 16 + ml) * 64];
        oacc[T][nb] = __builtin_amdgcn_mfma_f32_16x16x32_bf16(*(const bf16x8*)&vrow[(qd ^ sx) * 8],       pa0, oacc[T][nb], 0, 0, 0);
        oacc[T][nb] = __builtin_amdgcn_mfma_f32_16x16x32_bf16(*(const bf16x8*)&vrow[((qd + 4) ^ sx) * 8], pa1, oacc[T][nb], 0, 0, 0);
      }
    }
  }
#undef ISSUE

  // epilogue: lane owns query q0t[T]+ml; d = nb*16 + qd*4 + r (4 contiguous)
#pragma unroll
  for (int T = 0; T < 2; ++T) {
    const float inv = 1.0f / l_i[T];
    const int q = q0t[T] + ml;
#pragma unroll
    for (int nb = 0; nb < 4; ++nb) {
      uint2 o;
      o.x = pkbf(oacc[T][nb][0] * inv, oacc[T][nb][1] * inv);
      o.y = pkbf(oacc[T][nb][2] * inv, oacc[T][nb][3] * inv);
      *(uint2*)&Og[base + (size_t)q * E_ + nb * 16 + qd * 4] = o;
    }
  }
}

// ============================================================================
extern "C" void kernel_launch(void* const* d_in, const int* in_sizes, int n_in,
                              void* d_out, int out_size, void* d_ws, size_t ws_size,
                              hipStream_t stream) {
  const void* hs = d_in[0];
  const void* Wq = d_in[1];
  const void* bq = d_in[2];
  const void* Wk = d_in[3];
  const void* bk = d_in[4];
  const void* Wv = d_in[5];
  const void* bv = d_in[6];
  const void* Wp = d_in[7];
  const void* bp = d_in[8];

  ushort* ws = (ushort*)d_ws;
  ushort* hsb = ws + OFF_HSB;
  ushort* Wqb = ws + OFF_W(0);
  ushort* Wkb = ws + OFF_W(1);
  ushort* Wvb = ws + OFF_W(2);
  ushort* Wpb = ws + OFF_W(3);
  ushort* bqb = ws + OFF_B(0);
  ushort* bkb = ws + OFF_B(1);
  ushort* bvb = ws + OFF_B(2);
  ushort* bpb = ws + OFF_B(3);
  ushort* Qw  = ws + OFF_Q;
  ushort* Kw  = ws + OFF_K;
  ushort* Vw  = ws + OFF_V;   // V^T [feature][b*S+s]
  ushort* Ow  = ws + OFF_O;
  const ushort* det = (const ushort*)hs;

  dim3 blk(256, 1, 1);
  hipLaunchKernelGGL(convert_kernel, dim3(512, 9, 1), blk, 0, stream,
                     hs, Wq, Wk, Wv, Wp, bq, bk, bv, bp, ws);
  // fused QKV projections; z==2 (V) transposed store; z==0 (Q) scaled QSCALE
  hipLaunchKernelGGL(gemm_nt_bias, dim3(M_ / 128, E_ / 128, 3), blk, 0, stream,
                     hsb, Wqb, bqb, (void*)Qw, Wkb, bkb, (void*)Kw,
                     Wvb, bvb, (void*)Vw, M_, E_, E_, det, 0, 2, 0);
  // attention: 1024 1D blocks, XCD-swizzled
  hipLaunchKernelGGL(attn_kernel, dim3(1024, 1, 1), blk, 0, stream,
                     Qw, Kw, Vw, Ow);
  // output projection: d_out dtype detected at runtime
  hipLaunchKernelGGL(gemm_nt_bias, dim3(M_ / 128, E_ / 128, 1), blk, 0, stream,
                     Ow, Wpb, bpb, d_out, Wpb, bpb, d_out, Wpb, bpb, d_out,
                     M_, E_, E_, det, 1, -1, -1);
}